// Round 8
// baseline (380.322 us; speedup 1.0000x reference)
//
#include <hip/hip_runtime.h>
#include <hip/hip_bf16.h>
#include <hip/hip_fp8.h>
#include <math.h>

// Problem constants: b=4, c=64, h=w=256, WS=8, SHIFT=4, HEADS=4, d=16, hidden=256
// Windows: 32x32 per image * 4 images = 4096; 64 tokens/window.
//
// Workspace layout (peak 160 MB):
//   Cb  bf16 32MB [0,32M)    x3 token-major        written k2, read k3+k5
//   D   fp8  64MB [32,96M)   hid image layout      written k3, read k4
//   E   fp8  64MB [96,160M)  hid+conv image layout written k4, read k5
//   Wbf bf16 ~66KB at [96M): prep-converted qkvw/projw/rpb/fc1w (consumed
//       by k2/k3 before k4 overwrites E — stream order).
//   fc2w_bf at [32M): written by k_cvt AFTER k4 (D dead), read k5.
// R8: k_ln1 deleted — LN1 (per-token over c=64) + shortcut fused into k_attn,
//     which reads x directly. A/Bw buffers eliminated (~160MB HBM round-trips).

typedef __bf16  bf16x8  __attribute__((ext_vector_type(8)));
typedef float   f32x4   __attribute__((ext_vector_type(4)));
typedef float   f32x2   __attribute__((ext_vector_type(2)));
typedef unsigned short ushortx8 __attribute__((ext_vector_type(8)));

__device__ __forceinline__ float gelu_f(float v) {
    // tanh-form gelu: |err| <~2e-3, << fp8 step.
    float u = v * fmaf(0.0713548354f, v * v, 1.5957691216f);
    float t = __expf(u);
    float r = __builtin_amdgcn_rcpf(t + 1.0f);
    return v - v * r;
}
__device__ __forceinline__ unsigned char f32_to_fp8(float v) {
    __hip_fp8_e4m3 t(v);
    return (unsigned char)t.__x;
}
__device__ __forceinline__ float fp8_to_f32(unsigned char u) {
    __hip_fp8_e4m3 t;
    t.__x = (__hip_fp8_storage_t)u;
    return (float)t;
}

#if __has_builtin(__builtin_amdgcn_cvt_pk_f32_fp8) && __has_builtin(__builtin_amdgcn_cvt_pk_fp8_f32)
#define HW_FP8 1
#endif
template<bool HI>
__device__ __forceinline__ f32x2 fp8x2_f32(unsigned int u) {
#ifdef HW_FP8
    return __builtin_amdgcn_cvt_pk_f32_fp8((int)u, HI);
#else
    f32x2 r;
    const int s = HI ? 16 : 0;
    r.x = fp8_to_f32((unsigned char)(u >> s));
    r.y = fp8_to_f32((unsigned char)(u >> (s + 8)));
    return r;
#endif
}
template<bool HI>
__device__ __forceinline__ unsigned int f32x2_fp8(float a, float b, unsigned int old) {
#ifdef HW_FP8
    return (unsigned int)__builtin_amdgcn_cvt_pk_fp8_f32(a, b, (int)old, HI);
#else
    unsigned int v = (unsigned int)f32_to_fp8(a) | ((unsigned int)f32_to_fp8(b) << 8);
    return HI ? ((old & 0x0000ffffu) | (v << 16)) : ((old & 0xffff0000u) | v);
#endif
}

__device__ __forceinline__ unsigned short f2bf(float f) {   // RNE, matches HW
    unsigned int u = __builtin_bit_cast(unsigned int, f);
    u += 0x7fffu + ((u >> 16) & 1u);
    return (unsigned short)(u >> 16);
}
__device__ __forceinline__ float bf2f(unsigned short u) {
    return __builtin_bit_cast(float, ((unsigned int)u) << 16);
}
// packed f32x2 -> 2x bf16 in one dword (lo = a, hi = b); RNE, matches f2bf.
__device__ __forceinline__ unsigned int cvt_pk_bf16(float a, float b) {
#if defined(__gfx950__)
    unsigned int r;
    asm("v_cvt_pk_bf16_f32 %0, %1, %2" : "=v"(r) : "v"(a), "v"(b));
    return r;
#else
    return (unsigned int)f2bf(a) | ((unsigned int)f2bf(b) << 16);
#endif
}

// ---------------------------------------------------------------------------
// Kernel 0: one-time weight conversion to bf16.
// ---------------------------------------------------------------------------
__global__ __launch_bounds__(256) void k_prep(
        const float* __restrict__ qkvw, const float* __restrict__ projw,
        const float* __restrict__ rpb,  const float* __restrict__ fc1w,
        unsigned short* __restrict__ qkvw_bf, unsigned short* __restrict__ projw_bf,
        unsigned short* __restrict__ rpb_bf,  unsigned short* __restrict__ fc1w_bf) {
    const int i = blockIdx.x * 256 + threadIdx.x;   // grid 64*256 = 16384
    if (i < 12288) qkvw_bf[i] = f2bf(qkvw[i]);
    if (i < 4096)  projw_bf[i] = f2bf(projw[i]);
    if (i < 900)   rpb_bf[i]   = f2bf(rpb[i]);
    if (i < 16384) fc1w_bf[i]  = f2bf(fc1w[i]);
}

__global__ __launch_bounds__(256) void k_cvt(const float* __restrict__ src,
        unsigned short* __restrict__ dst, int n) {
    const int i = blockIdx.x * 256 + threadIdx.x;
    if (i < n) dst[i] = f2bf(src[i]);
}

// ---------------------------------------------------------------------------
// Kernel 2: fused LN1 + windowed attention, MFMA bf16.
// Reads x directly (window tokens = image rows/cols (w*8+p+4)&255 — the SAME
// positions the shortcut residual needs, so one read serves both).
// LDS time-share: Ws region = rawT f32[64][68] during LN, then qkvw staging,
// then Q/K/V/P/projw (R5 softmax: no reductions, ones-MFMA row sums).
// LN scratch overlays Xs (red) / projbl (mu) / qkvbl (lnw,lnb,rs); biases
// re-written from registers after the LN phase. LDS unchanged -> 4 blocks/CU.
// ---------------------------------------------------------------------------
__global__ __launch_bounds__(256) void k_attn(
        const float* __restrict__ x,
        const float* __restrict__ n1w, const float* __restrict__ n1b,
        const unsigned short* __restrict__ qkvw_bf,
        const unsigned short* __restrict__ projw_bf,
        const unsigned short* __restrict__ rpb_bf,
        const float* __restrict__ qkvb,
        const float* __restrict__ projb,
        unsigned short* __restrict__ Cb) {
    __shared__ __align__(16) unsigned short Xs[4608];    // [64][72]; LN: red0/red1
    __shared__ __align__(16) unsigned short Ws[13824];   // rawT f32 -> W -> QKV/P/projw
    __shared__ __align__(8)  unsigned short rpbl[900];
    __shared__ float qkvbl[192];                         // LN: lnw/lnb/rs -> qkv bias
    __shared__ float projbl[64];                         // LN: mu -> proj bias

    const int tid = threadIdx.x;
    const int lane = tid & 63, wv = tid >> 6;
    const int l15 = lane & 15, quad = lane >> 4;
    const int widx = blockIdx.x;
    const int wib = widx & 1023;
    const int wy = wib >> 5, wx = wib & 31, bimg = widx >> 10;
    const bool edge = (wy == 31) | (wx == 31);

    const f32x4 zz = {0.f, 0.f, 0.f, 0.f};
    const ushortx8 zu = {0, 0, 0, 0, 0, 0, 0, 0};
    const bf16x8 z8 = __builtin_bit_cast(bf16x8, zu);
    const ushortx8 ou = {0x3F80, 0x3F80, 0x3F80, 0x3F80, 0x3F80, 0x3F80, 0x3F80, 0x3F80};
    const bf16x8 ones8 = __builtin_bit_cast(bf16x8, ou);

    float* rawT = (float*)Ws;                 // [64 ch][68] f32 (17408B <= 27648B)
    float* red0 = (float*)Xs;                 // [256]
    float* red1 = red0 + 256;                 // [256]
    float* lnw  = qkvbl;                      // [64]
    float* lnb  = qkvbl + 64;                 // [64]
    float* rsv  = qkvbl + 128;                // [64]
    float* muv  = projbl;                     // [64]

    // register-held biases (LDS slots busy during LN phase)
    float qb = 0.f, pb = 0.f;
    if (tid < 192) qb = qkvb[tid];
    if (tid < 64)  pb = projb[tid];
    if (tid < 64)  { lnw[tid] = n1w[tid]; lnb[tid] = n1b[tid]; }

    // prefetch projw (consumed after B4)
    const ushortx8 pw0 = *(const ushortx8*)(projw_bf + tid * 8);
    const ushortx8 pw1 = *(const ushortx8*)(projw_bf + (256 + tid) * 8);

    if (tid < 225) *(uint2*)&rpbl[tid * 4] = *(const uint2*)(rpb_bf + tid * 4);

    // stage x: 1024 units = 64ch x 8py x 2half; float4 each; wrap via &255
    // (first chunk col0 = wx*8+4 <= 252 never wraps; second wraps only wx=31).
    {
        const float* xb = x + (((size_t)bimg * 64) << 16);
        #pragma unroll
        for (int it = 0; it < 4; ++it) {
            const int u = it * 256 + tid;
            const int ch = u >> 4, py = (u >> 1) & 7, half = u & 1;
            const int iy = (wy * 8 + py + 4) & 255;
            const int col0 = (wx * 8 + 4 + half * 4) & 255;
            const float4 v = *(const float4*)(xb + ((size_t)ch << 16) + iy * 256 + col0);
            f32x4 w4 = {v.x, v.y, v.z, v.w};
            *(f32x4*)&rawT[ch * 68 + py * 8 + half * 4] = w4;
        }
    }
    __syncthreads();                                // B_a (rawT visible)

    // LN stats: tokens are columns of rawT
    {
        const int tk = tid & 63, cl = tid >> 6;
        float s = 0.f, s2 = 0.f;
        #pragma unroll
        for (int k = 0; k < 16; ++k) {
            float v = rawT[(cl * 16 + k) * 68 + tk];
            s += v; s2 += v * v;
        }
        red0[cl * 64 + tk] = s; red1[cl * 64 + tk] = s2;
    }
    __syncthreads();                                // B_b
    if (tid < 64) {
        float s  = red0[tid] + red0[64 + tid] + red0[128 + tid] + red0[192 + tid];
        float s2 = red1[tid] + red1[64 + tid] + red1[128 + tid] + red1[192 + tid];
        float mu = s * (1.f / 64.f);
        float var = s2 * (1.f / 64.f) - mu * mu;
        muv[tid] = mu; rsv[tid] = rsqrtf(var + 1e-5f);
    }
    __syncthreads();                                // B_b2

    // normalize -> Xs (paired channels, cvt_pk); extract residual to regs
    {
        const int cp = tid & 31, ch0 = cp * 2, tl = tid >> 5;
        const float lw0 = lnw[ch0], lw1 = lnw[ch0 + 1];
        const float lb0 = lnb[ch0], lb1 = lnb[ch0 + 1];
        #pragma unroll
        for (int it = 0; it < 8; ++it) {
            const int t = tl + 8 * it;
            const float v0 = rawT[ch0 * 68 + t];
            const float v1 = rawT[(ch0 + 1) * 68 + t];
            const float mu = muv[t], rs = rsv[t];
            const float vn0 = (v0 - mu) * rs * lw0 + lb0;
            const float vn1 = (v1 - mu) * rs * lw1 + lb1;
            *(unsigned int*)&Xs[t * 72 + ch0] = cvt_pk_bf16(vn0, vn1);
        }
    }
    float residf[16];
    #pragma unroll
    for (int r = 0; r < 4; ++r) {
        const int tok = 16 * wv + quad * 4 + r;
        #pragma unroll
        for (int nt = 0; nt < 4; ++nt)
            residf[r * 4 + nt] = rawT[(nt * 16 + l15) * 68 + tok];
    }
    __syncthreads();                                // B_c (rawT/mu/rs dead)

    // restore bias tables; stage full qkvw (192 rows, b128)
    if (tid < 192) qkvbl[tid] = qb;
    if (tid < 64)  projbl[tid] = pb;
    #pragma unroll
    for (int it = 0; it < 6; ++it) {
        int g = it * 256 + tid;
        int row = g >> 3, c8 = g & 7;
        *(ushortx8*)&Ws[row * 72 + c8 * 8] = *(const ushortx8*)(qkvw_bf + g * 8);
    }
    __syncthreads();                                // B1

    // QKV: 24 MFMA/thread
    f32x4 qacc[12];
    #pragma unroll
    for (int i = 0; i < 12; ++i) qacc[i] = zz;
    {
        const bf16x8 av0 = *(const bf16x8*)&Xs[(16 * wv + l15) * 72 + quad * 8];
        const bf16x8 av1 = *(const bf16x8*)&Xs[(16 * wv + l15) * 72 + 32 + quad * 8];
        #pragma unroll
        for (int gl = 0; gl < 12; ++gl) {
            bf16x8 bv0 = *(const bf16x8*)&Ws[(gl * 16 + l15) * 72 + quad * 8];
            qacc[gl] = __builtin_amdgcn_mfma_f32_16x16x32_bf16(av0, bv0, qacc[gl], 0, 0, 0);
            bf16x8 bv1 = *(const bf16x8*)&Ws[(gl * 16 + l15) * 72 + 32 + quad * 8];
            qacc[gl] = __builtin_amdgcn_mfma_f32_16x16x32_bf16(av1, bv1, qacc[gl], 0, 0, 0);
        }
    }
    __syncthreads();                                // B2 (all W reads done)

    // write Q (scaled) / K / V into Ws
    #pragma unroll
    for (int g = 0; g < 12; ++g) {
        #pragma unroll
        for (int r = 0; r < 4; ++r) {
            int tok = 16 * wv + quad * 4 + r;
            int oc  = g * 16 + l15;
            float v = qacc[g][r] + qkvbl[oc];
            if (g < 4)       Ws[g * 1024 + tok * 16 + l15] = f2bf(v * 0.25f);
            else if (g < 8)  Ws[4096 + (g - 4) * 1024 + tok * 16 + l15] = f2bf(v);
            else             Ws[8192 + ((g - 8) * 16 + l15) * 72 + tok] = f2bf(v);
        }
    }
    __syncthreads();                                // B3

    // S = Q K^T
    f32x4 sacc[4][4];
    #pragma unroll
    for (int h = 0; h < 4; ++h) {
        bf16x8 qa = z8;
        if (quad < 2) qa = *(const bf16x8*)&Ws[h * 1024 + (16 * wv + l15) * 16 + quad * 8];
        #pragma unroll
        for (int nt = 0; nt < 4; ++nt) {
            bf16x8 kf = z8;
            if (quad < 2) kf = *(const bf16x8*)&Ws[4096 + h * 1024 + (nt * 16 + l15) * 16 + quad * 8];
            sacc[h][nt] = __builtin_amdgcn_mfma_f32_16x16x32_bf16(qa, kf, zz, 0, 0, 0);
        }
    }
    __syncthreads();                                // B4

    // stage projw into the dead K region, XOR-swizzled [oc][64]
    {
        const int r0 = tid >> 3;
        *(ushortx8*)&Ws[4096 + r0 * 64 + (((tid & 7) ^ (r0 & 7)) << 3)] = pw0;
        const int g1 = 256 + tid, r1 = g1 >> 3;
        *(ushortx8*)&Ws[4096 + r1 * 64 + (((g1 & 7) ^ (r1 & 7)) << 3)] = pw1;
    }

    const int jhi = l15 >> 3, jlo = l15 & 7;
    int offj4[4], regj[4];
    #pragma unroll
    for (int nt = 0; nt < 4; ++nt) {
        int j = nt * 16 + l15;
        int jy = j >> 3, jx = j & 7;
        offj4[nt] = (jy * 15 + jx) * 4;
        regj[nt] = 0;
        if (edge) {
            int ysj = wy * 8 + jy, xsj = wx * 8 + jx;
            regj[nt] = (ysj >= 252 ? 2 : (ysj >= 248 ? 1 : 0)) * 3
                     + (xsj >= 252 ? 2 : (xsj >= 248 ? 1 : 0));
        }
    }
    int rbA[4], regiA[4], pbaseA[4], i7A[4];
    #pragma unroll
    for (int r = 0; r < 4; ++r) {
        const int i = 16 * wv + quad * 4 + r;
        const int iy = i >> 3, ix = i & 7;
        rbA[r] = ((iy + 7) * 15 + (ix + 7)) * 4;
        i7A[r] = i & 7;
        pbaseA[r] = i * 64 + jlo;
        regiA[r] = 0;
        if (edge) {
            const int ysi = wy * 8 + iy, xsi = wx * 8 + ix;
            regiA[r] = (ysi >= 252 ? 2 : (ysi >= 248 ? 1 : 0)) * 3
                     + (xsi >= 252 ? 2 : (xsi >= 248 ? 1 : 0));
        }
    }

    #pragma unroll
    for (int r = 0; r < 4; ++r) {
        #pragma unroll
        for (int nt = 0; nt < 4; ++nt) {
            const uint2 bw = *(const uint2*)&rpbl[rbA[r] - offj4[nt]];
            float mk = 0.f;
            if (edge) mk = (regj[nt] == regiA[r]) ? 0.f : -100.f;
            sacc[0][nt][r] += __builtin_bit_cast(float, bw.x << 16) + mk;
            sacc[1][nt][r] += __builtin_bit_cast(float, bw.x & 0xffff0000u) + mk;
            sacc[2][nt][r] += __builtin_bit_cast(float, bw.y << 16) + mk;
            sacc[3][nt][r] += __builtin_bit_cast(float, bw.y & 0xffff0000u) + mk;
        }
    }
    int pA_[4][4];
    #pragma unroll
    for (int r = 0; r < 4; ++r)
        #pragma unroll
        for (int nt = 0; nt < 4; ++nt)
            pA_[r][nt] = pbaseA[r] + ((((nt << 1) | jhi) ^ i7A[r]) << 3);

    // per-head: exp (no reductions) -> P bf16 (unnormalized) -> PV + ones-MFMA
    f32x4 o[4];
    #pragma unroll
    for (int h = 0; h < 4; ++h) {
        #pragma unroll
        for (int r = 0; r < 4; ++r) {
            const unsigned int pk01 = cvt_pk_bf16(__expf(sacc[h][0][r]),
                                                  __expf(sacc[h][1][r]));
            const unsigned int pk23 = cvt_pk_bf16(__expf(sacc[h][2][r]),
                                                  __expf(sacc[h][3][r]));
            Ws[pA_[r][0]] = (unsigned short)pk01;
            Ws[pA_[r][1]] = (unsigned short)(pk01 >> 16);
            Ws[pA_[r][2]] = (unsigned short)pk23;
            Ws[pA_[r][3]] = (unsigned short)(pk23 >> 16);
        }
        o[h] = zz;
        f32x4 os = zz;
        #pragma unroll
        for (int s = 0; s < 2; ++s) {
            bf16x8 pa = *(const bf16x8*)&Ws[(16 * wv + l15) * 64
                                            + (((s * 4 + quad) ^ (l15 & 7)) << 3)];
            bf16x8 vb = *(const bf16x8*)&Ws[8192 + (h * 16 + l15) * 72 + s * 32 + quad * 8];
            o[h] = __builtin_amdgcn_mfma_f32_16x16x32_bf16(pa, vb, o[h], 0, 0, 0);
            os   = __builtin_amdgcn_mfma_f32_16x16x32_bf16(pa, ones8, os, 0, 0, 0);
        }
        #pragma unroll
        for (int r = 0; r < 4; ++r) o[h][r] *= __builtin_amdgcn_rcpf(os[r]);
    }

    // o -> Xs (own rows only)
    #pragma unroll
    for (int h = 0; h < 4; ++h)
        #pragma unroll
        for (int r = 0; r < 4; ++r)
            Xs[(16 * wv + quad * 4 + r) * 72 + h * 16 + l15] = f2bf(o[h][r]);
    __syncthreads();                                // B5

    // proj: 8 MFMA/thread
    f32x4 pacc[4];
    #pragma unroll
    for (int nt = 0; nt < 4; ++nt) {
        pacc[nt] = zz;
        #pragma unroll
        for (int s = 0; s < 2; ++s) {
            bf16x8 oa = *(const bf16x8*)&Xs[(16 * wv + l15) * 72 + s * 32 + quad * 8];
            bf16x8 wb = *(const bf16x8*)&Ws[4096 + (nt * 16 + l15) * 64
                                            + (((s * 4 + quad) ^ (l15 & 7)) << 3)];
            pacc[nt] = __builtin_amdgcn_mfma_f32_16x16x32_bf16(oa, wb, pacc[nt], 0, 0, 0);
        }
    }

    // epilogue: bias + residual (f32, from registers), un-shift, store Cb
    #pragma unroll
    for (int r = 0; r < 4; ++r) {
        int tok = 16 * wv + quad * 4 + r;
        int py = tok >> 3, px = tok & 7;
        int yo = (wy * 8 + py + 4) & 255, xo = (wx * 8 + px + 4) & 255;
        size_t gt = ((size_t)bimg << 16) + yo * 256 + xo;
        #pragma unroll
        for (int nt = 0; nt < 4; ++nt) {
            int oc = nt * 16 + l15;
            float v = pacc[nt][r] + projbl[oc] + residf[r * 4 + nt];
            Cb[gt * 64 + oc] = f2bf(v);
        }
    }
}

// ---------------------------------------------------------------------------
// Kernel 3: LN2 + fc1 + GELU -> D (image layout fp8), MFMA bf16 (R7).
// ---------------------------------------------------------------------------
__global__ __launch_bounds__(256) void k_ln2fc1(const unsigned short* __restrict__ Cb,
        const float* __restrict__ w2, const float* __restrict__ b2,
        const unsigned short* __restrict__ fc1w_bf, const float* __restrict__ fc1b,
        unsigned char* __restrict__ D) {
    __shared__ __align__(16) unsigned short Xb[64 * 72];    // raw->normalized bf16
    __shared__ __align__(16) unsigned short Wb[256 * 72];   // fc1w bf16; tail reuse: stT
    __shared__ float red0[256], red1[256];
    __shared__ float muv[64], rsv[64], lwv[64], lbv[64], fb[256];
    const int tid = threadIdx.x, gid = blockIdx.x;
    const int xc = gid & 3, y = (gid >> 2) & 255, b = gid >> 10;
    const int x0 = xc * 64;
    const int lane = tid & 63, wv = tid >> 6;
    const int l15 = lane & 15, quad = lane >> 4;
    const f32x4 zz = {0.f, 0.f, 0.f, 0.f};

    if (tid < 64) { lwv[tid] = w2[tid]; lbv[tid] = b2[tid]; }
    fb[tid] = fc1b[tid];

    // stage Cb -> Xb (b128, 2 passes)
    const unsigned short* Cp = Cb + ((size_t)(b << 16) + y * 256 + x0) * 64;
    #pragma unroll
    for (int it = 0; it < 2; ++it) {
        const int g = it * 256 + tid;               // granule 0..511
        const int row = g >> 3, c8 = g & 7;
        *(ushortx8*)&Xb[row * 72 + c8 * 8] = *(const ushortx8*)(Cp + g * 8);
    }
    // stage fc1w_bf -> Wb (b128)
    {
        const ushortx8* w8 = (const ushortx8*)fc1w_bf;
        #pragma unroll
        for (int it = 0; it < 8; ++it) {
            int idx = it * 256 + tid;
            int row = idx >> 3, c8 = idx & 7;
            *(ushortx8*)&Wb[row * 72 + c8 * 8] = w8[idx];
        }
    }
    __syncthreads();
    // LN stats from bf16 tile
    {
        const int tok = tid & 63, cl = tid >> 6;
        float s = 0.f, s2 = 0.f;
        #pragma unroll
        for (int g = 0; g < 2; ++g) {
            const ushortx8 u = *(const ushortx8*)&Xb[tok * 72 + cl * 16 + g * 8];
            #pragma unroll
            for (int k = 0; k < 8; ++k) { float v = bf2f(u[k]); s += v; s2 += v * v; }
        }
        red0[cl * 64 + tok] = s; red1[cl * 64 + tok] = s2;
    }
    __syncthreads();
    if (tid < 64) {
        float s  = red0[tid] + red0[64 + tid] + red0[128 + tid] + red0[192 + tid];
        float s2 = red1[tid] + red1[64 + tid] + red1[128 + tid] + red1[192 + tid];
        float mu = s * (1.f / 64.f);
        float var = s2 * (1.f / 64.f) - mu * mu;
        muv[tid] = mu; rsv[tid] = rsqrtf(var + 1e-5f);
    }
    __syncthreads();
    // normalize in place (vectorized: b128 read/write, cvt_pk pack)
    {
        const int c8n = tid & 7;
        const float4 lwa = *(const float4*)&lwv[c8n * 8];
        const float4 lwb2 = *(const float4*)&lwv[c8n * 8 + 4];
        const float4 lba = *(const float4*)&lbv[c8n * 8];
        const float4 lbb2 = *(const float4*)&lbv[c8n * 8 + 4];
        const float lw8[8] = {lwa.x, lwa.y, lwa.z, lwa.w, lwb2.x, lwb2.y, lwb2.z, lwb2.w};
        const float lb8[8] = {lba.x, lba.y, lba.z, lba.w, lbb2.x, lbb2.y, lbb2.z, lbb2.w};
        #pragma unroll
        for (int it = 0; it < 2; ++it) {
            const int row = it * 32 + (tid >> 3);
            const ushortx8 u = *(const ushortx8*)&Xb[row * 72 + c8n * 8];
            const float mu = muv[row], rs = rsv[row];
            float v[8];
            #pragma unroll
            for (int k = 0; k < 8; ++k) v[k] = (bf2f(u[k]) - mu) * rs * lw8[k] + lb8[k];
            uint4 pk;
            pk.x = cvt_pk_bf16(v[0], v[1]); pk.y = cvt_pk_bf16(v[2], v[3]);
            pk.z = cvt_pk_bf16(v[4], v[5]); pk.w = cvt_pk_bf16(v[6], v[7]);
            *(uint4*)&Xb[row * 72 + c8n * 8] = pk;
        }
    }
    __syncthreads();

    // MFMA: acc[mt][nt], m = 64wv+16mt (hidden ch), n = 16nt (token), K=64
    f32x4 acc[4][4];
    #pragma unroll
    for (int mt = 0; mt < 4; ++mt)
        #pragma unroll
        for (int nt = 0; nt < 4; ++nt) acc[mt][nt] = zz;
    #pragma unroll
    for (int s = 0; s < 2; ++s) {
        bf16x8 Bf[4];
        #pragma unroll
        for (int nt = 0; nt < 4; ++nt)
            Bf[nt] = *(const bf16x8*)&Xb[(nt * 16 + l15) * 72 + s * 32 + quad * 8];
        #pragma unroll
        for (int mt = 0; mt < 4; ++mt) {
            bf16x8 Af = *(const bf16x8*)&Wb[(64 * wv + 16 * mt + l15) * 72 + s * 32 + quad * 8];
            #pragma unroll
            for (int nt = 0; nt < 4; ++nt)
                acc[mt][nt] = __builtin_amdgcn_mfma_f32_16x16x32_bf16(Af, Bf[nt], acc[mt][nt], 0, 0, 0);
        }
    }

    // epilogue: bias + gelu + fp8 pack -> wave-private LDS transpose ->
    // coalesced u32 stores.
    unsigned int* stT = (unsigned int*)&Wb[(size_t)(64 * wv) * 72]; // [16][20] u32
    const int s4 = lane >> 4;
    #pragma unroll
    for (int mt = 0; mt < 4; ++mt) {
        #pragma unroll
        for (int r = 0; r < 4; ++r) {
            const int mch = 64 * wv + 16 * mt + quad * 4 + r;
            const float bias = fb[mch];
            float g0 = gelu_f(acc[mt][0][r] + bias);
            float g1 = gelu_f(acc[mt][1][r] + bias);
            float g2 = gelu_f(acc[mt][2][r] + bias);
            float g3 = gelu_f(acc[mt][3][r] + bias);
            unsigned int pk = f32x2_fp8<false>(g0, g1, 0u);
            pk = f32x2_fp8<true>(g2, g3, pk);
            stT[(quad * 4 + r) * 20 + l15] = pk;
        }
        const int orow = l15;
        const uint4 w = *(const uint4*)&stT[orow * 20 + 4 * s4];
        const int mch2 = 64 * wv + 16 * mt + orow;
        unsigned char* Dp2 = D + (((size_t)(b * 256 + mch2)) << 16) + y * 256 + x0;
        #pragma unroll
        for (int p = 0; p < 4; ++p) {
            unsigned int o = ((w.x >> (8 * p)) & 0xffu)
                           | (((w.y >> (8 * p)) & 0xffu) << 8)
                           | (((w.z >> (8 * p)) & 0xffu) << 16)
                           | (((w.w >> (8 * p)) & 0xffu) << 24);
            *(unsigned int*)&Dp2[16 * p + 4 * s4] = o;
        }
    }
}

// ---------------------------------------------------------------------------
// Kernel 4: depthwise 5x5 conv + GELU + residual via MFMA (banded matmul, R7).
// ---------------------------------------------------------------------------
__global__ __launch_bounds__(256) void k_dwconv(const unsigned char* __restrict__ D,
        const float* __restrict__ dww, const float* __restrict__ dwb,
        unsigned char* __restrict__ E) {
    __shared__ __align__(16) unsigned short inT[36 * 280 + 16]; // [t][2+x]
    __shared__ __align__(16) unsigned short Atab[5 * 64 * 8];   // A frags per ky
    __shared__ __align__(16) unsigned char outT[4][16 * 144];   // per-wave staging
    const int tid = threadIdx.x, gid = blockIdx.x;
    const int yt = gid & 7, pc = gid >> 3;        // grid 8192
    const int ch = pc & 255;
    const int y0 = yt * 32;
    const unsigned char* Dp = D + ((size_t)pc << 16);
    const f32x4 zz = {0.f, 0.f, 0.f, 0.f};

    // pad columns: dword 0 + dwords 129..139
    for (int idx = tid; idx < 432; idx += 256) {
        const int r = idx / 12, c = idx - r * 12;
        const int dw = (c == 0) ? 0 : (128 + c);
        ((unsigned int*)&inT[r * 280])[dw] = 0u;
    }
    // stage D (fp8) -> inT (bf16); OOB rows write zeros
    #pragma unroll
    for (int it = 0; it < 9; ++it) {
        const int u = it * 256 + tid;
        const int t = u >> 6, c = u & 63;
        const int gy = y0 - 2 + t;
        unsigned int v = 0u;
        if ((unsigned)gy < 256u) v = *(const unsigned int*)(Dp + gy * 256 + 4 * c);
        const f32x2 lo = fp8x2_f32<false>(v);
        const f32x2 hi = fp8x2_f32<true>(v);
        unsigned int* base = (unsigned int*)&inT[t * 280 + 2 + 4 * c];
        base[0] = cvt_pk_bf16(lo.x, lo.y);
        base[1] = cvt_pk_bf16(hi.x, hi.y);
    }
    // A-fragment table
    #pragma unroll
    for (int q = 0; q < 10; ++q) {
        const int e = tid * 10 + q;               // 0..2559
        const int ky = e >> 9, r = e & 511;
        const int l = r >> 3, j = r & 7;
        const int m = l & 15, k = ((l >> 4) << 3) + j;
        const int d = k - m;
        float wv = 0.f;
        if (d >= 0 && d < 5) wv = dww[ch * 25 + ky * 5 + d];
        Atab[e] = f2bf(wv);
    }
    const float bb = dwb[ch];
    __syncthreads();

    const int wv_ = tid >> 6, lane = tid & 63;
    const int l15 = lane & 15, quad = lane >> 4;
    const int g = wv_ >> 1, xh = wv_ & 1;
    bf16x8 Af[5];
    #pragma unroll
    for (int ky = 0; ky < 5; ++ky)
        Af[ky] = *(const bf16x8*)&Atab[(ky * 64 + lane) * 8];
    const int tbase = g * 16 + l15;

    #pragma unroll
    for (int xp = 0; xp < 8; ++xp) {
        const int xs = xh * 128 + xp * 16;
        f32x4 acc = zz;
        #pragma unroll
        for (int ky = 0; ky < 5; ++ky) {
            bf16x8 Bf = *(const bf16x8*)&inT[(tbase + ky) * 280 + xs + quad * 8];
            acc = __builtin_amdgcn_mfma_f32_16x16x32_bf16(Af[ky], Bf, acc, 0, 0, 0);
        }
        const unsigned int* cp32 = (const unsigned int*)&inT[(tbase + 2) * 280 + 2 + xs + quad * 4];
        const unsigned int c01 = cp32[0], c23 = cp32[1];
        const float c0 = bf2f((unsigned short)c01), c1 = bf2f((unsigned short)(c01 >> 16));
        const float c2 = bf2f((unsigned short)c23), c3 = bf2f((unsigned short)(c23 >> 16));
        unsigned int pk = f32x2_fp8<false>(c0 + gelu_f(acc[0] + bb), c1 + gelu_f(acc[1] + bb), 0u);
        pk = f32x2_fp8<true>(c2 + gelu_f(acc[2] + bb), c3 + gelu_f(acc[3] + bb), pk);
        *(unsigned int*)&outT[wv_][l15 * 144 + xp * 16 + quad * 4] = pk;
    }

    {
        const int row = lane >> 2, sg = lane & 3;
        unsigned char* Ep = E + ((size_t)pc << 16) + (y0 + g * 16 + row) * 256 + xh * 128 + sg * 32;
        *(uint4*)Ep        = *(const uint4*)&outT[wv_][row * 144 + sg * 32];
        *(uint4*)(Ep + 16) = *(const uint4*)&outT[wv_][row * 144 + sg * 32 + 16];
    }
}

// ---------------------------------------------------------------------------
// Kernel 5: fc2 + bias + residual + transpose -> out (b,c,h,w) fp32, MFMA (R7).
// ---------------------------------------------------------------------------
__global__ __launch_bounds__(256) void k_fc2(const unsigned char* __restrict__ E,
        const unsigned short* __restrict__ Cb, const unsigned short* __restrict__ fc2w_bf,
        const float* __restrict__ fc2b, float* __restrict__ out) {
    __shared__ __align__(16) unsigned short Hb[64 * 136];   // [tok][k128 swz]
    __shared__ __align__(16) unsigned short Wb2[64 * 264];  // [oc][k256]
    __shared__ __align__(16) unsigned short Cl[64 * 72];    // residual raw bf16
    __shared__ float fbl[64];
    const int tid = threadIdx.x, gid = blockIdx.x;
    const int xc = gid & 3, y = (gid >> 2) & 255, b = gid >> 10;
    const int x0 = xc * 64;
    const int lane = tid & 63, wv = tid >> 6;
    const int l15 = lane & 15, quad = lane >> 4;
    const f32x4 zz = {0.f, 0.f, 0.f, 0.f};

    if (tid < 64) fbl[tid] = fc2b[tid];
    {
        const unsigned short* Cp = Cb + ((size_t)(b << 16) + y * 256 + x0) * 64;
        #pragma unroll
        for (int it = 0; it < 2; ++it) {
            const int g = it * 256 + tid;
            const int row = g >> 3, c8 = g & 7;
            *(ushortx8*)&Cl[row * 72 + c8 * 8] = *(const ushortx8*)(Cp + g * 8);
        }
    }
    {
        const ushortx8* w8 = (const ushortx8*)fc2w_bf;
        #pragma unroll
        for (int it = 0; it < 8; ++it) {
            int idx = it * 256 + tid;
            int row = idx >> 5, c8 = idx & 31;
            *(ushortx8*)&Wb2[row * 264 + c8 * 8] = w8[idx];
        }
    }

    f32x4 acc[4];
    #pragma unroll
    for (int nt = 0; nt < 4; ++nt) acc[nt] = zz;

    const int ldc = tid >> 4;
    const int tq  = tid & 15;
    unsigned int u0[8];
    #pragma unroll
    for (int it = 0; it < 8; ++it) {
        int chl = ldc + 16 * it;
        u0[it] = *(const unsigned int*)&E[(((size_t)(b * 256 + chl)) << 16) + y * 256 + x0 + 4 * tq];
    }
    __syncthreads();

    for (int kc = 0; kc < 2; ++kc) {
        #pragma unroll
        for (int it = 0; it < 8; ++it) {
            int chl = ldc + 16 * it;
            f32x2 lo = fp8x2_f32<false>(u0[it]);
            f32x2 hi = fp8x2_f32<true>(u0[it]);
            const unsigned int p01 = cvt_pk_bf16(lo.x, lo.y);
            const unsigned int p23 = cvt_pk_bf16(hi.x, hi.y);
            unsigned short hs[4] = {(unsigned short)p01, (unsigned short)(p01 >> 16),
                                    (unsigned short)p23, (unsigned short)(p23 >> 16)};
            #pragma unroll
            for (int j = 0; j < 4; ++j) {
                int tok = 4 * tq + j;
                int p = (((chl >> 3) ^ (tok >> 2)) << 3) + (chl & 7);
                Hb[tok * 136 + p] = hs[j];
            }
        }
        if (kc == 0) {
            #pragma unroll
            for (int it = 0; it < 8; ++it) {
                int chl = ldc + 16 * it + 128;
                u0[it] = *(const unsigned int*)&E[(((size_t)(b * 256 + chl)) << 16) + y * 256 + x0 + 4 * tq];
            }
        }
        __syncthreads();
        #pragma unroll
        for (int k32 = 0; k32 < 4; ++k32) {
            bf16x8 Af = *(const bf16x8*)&Wb2[(16 * wv + l15) * 264 + kc * 128 + k32 * 32 + quad * 8];
            const int g = k32 * 4 + quad;
            #pragma unroll
            for (int nt = 0; nt < 4; ++nt) {
                const int tok = nt * 16 + l15;
                bf16x8 Bf = *(const bf16x8*)&Hb[tok * 136 + ((g ^ (tok >> 2)) << 3)];
                acc[nt] = __builtin_amdgcn_mfma_f32_16x16x32_bf16(Af, Bf, acc[nt], 0, 0, 0);
            }
        }
        if (kc == 0) __syncthreads();
    }

    #pragma unroll
    for (int r = 0; r < 4; ++r) {
        const int oc = 16 * wv + quad * 4 + r;
        const float bias = fbl[oc];
        float* op = out + (((size_t)(b * 64 + oc)) << 16) + y * 256 + x0;
        #pragma unroll
        for (int nt = 0; nt < 4; ++nt) {
            const int tok = nt * 16 + l15;
            op[tok] = acc[nt][r] + bias + bf2f(Cl[tok * 72 + oc]);
        }
    }
}

// ---------------------------------------------------------------------------
extern "C" void kernel_launch(void* const* d_in, const int* in_sizes, int n_in,
                              void* d_out, int out_size, void* d_ws, size_t ws_size,
                              hipStream_t stream) {
    const float* x     = (const float*)d_in[0];
    const float* n1w   = (const float*)d_in[1];
    const float* n1b   = (const float*)d_in[2];
    const float* qkvw  = (const float*)d_in[3];
    const float* qkvb  = (const float*)d_in[4];
    const float* rpb   = (const float*)d_in[5];
    const float* projw = (const float*)d_in[6];
    const float* projb = (const float*)d_in[7];
    const float* n2w   = (const float*)d_in[8];
    const float* n2b   = (const float*)d_in[9];
    const float* fc1w  = (const float*)d_in[10];
    const float* fc1b  = (const float*)d_in[11];
    const float* dww   = (const float*)d_in[12];
    const float* dwb   = (const float*)d_in[13];
    const float* fc2w  = (const float*)d_in[14];
    const float* fc2b  = (const float*)d_in[15];
    float* out = (float*)d_out;

    char* ws = (char*)d_ws;
    const size_t MB = 1048576;
    unsigned short* Cbuf = (unsigned short*)ws;                  // [0,32M)
    unsigned char*  Dh   = (unsigned char*)(ws + 32 * MB);       // [32,96M)
    unsigned char*  Eh   = (unsigned char*)(ws + 96 * MB);       // [96,160M)

    unsigned short* qkvw_bf = (unsigned short*)(ws + 96 * MB);
    unsigned short* projw_bf = (unsigned short*)(ws + 96 * MB + 24576);
    unsigned short* rpb_bf   = (unsigned short*)(ws + 96 * MB + 32768);
    unsigned short* fc1w_bf  = (unsigned short*)(ws + 96 * MB + 34816);
    unsigned short* fc2w_bf  = (unsigned short*)(ws + 32 * MB);

    k_prep  <<<64,    256, 0, stream>>>(qkvw, projw, rpb, fc1w,
                                        qkvw_bf, projw_bf, rpb_bf, fc1w_bf);
    k_attn  <<<4096,  256, 0, stream>>>(x, n1w, n1b, qkvw_bf, projw_bf, rpb_bf,
                                        qkvb, projb, Cbuf);
    k_ln2fc1<<<4096,  256, 0, stream>>>(Cbuf, n2w, n2b, fc1w_bf, fc1b, Dh);
    k_dwconv<<<8192,  256, 0, stream>>>(Dh, dww, dwb, Eh);
    k_cvt   <<<64,    256, 0, stream>>>(fc2w, fc2w_bf, 16384);
    k_fc2   <<<4096,  256, 0, stream>>>(Eh, Cbuf, fc2w_bf, fc2b, out);
}

// Round 9
// 345.767 us; speedup vs baseline: 1.0999x; 1.0999x over previous
//
#include <hip/hip_runtime.h>
#include <hip/hip_bf16.h>
#include <hip/hip_fp8.h>
#include <math.h>

// Problem constants: b=4, c=64, h=w=256, WS=8, SHIFT=4, HEADS=4, d=16, hidden=256
// Windows: 32x32 per image * 4 images = 4096; 64 tokens/window.
//
// Workspace layout (peak 160 MB):
//   Cb  bf16 32MB [0,32M)    x3 token-major        written k2, read k3+k5
//   D   fp8  64MB [32,96M)   hid image layout      written k3, read k4
//   E   fp8  64MB [96,160M)  hid+conv image layout written k4, read k5
//   Wbf bf16 ~66KB at [96M): prep-converted qkvw/projw/rpb/fc1w
//   fc2w_bf at [32M): written by k_cvt AFTER k4 (D dead), read k5.
// R9: k_attn gets XCD-aware block swizzle (x-adjacent windows share L2 lines)
//     + qkvw register prefetch (latency hidden under LN phase).

typedef __bf16  bf16x8  __attribute__((ext_vector_type(8)));
typedef float   f32x4   __attribute__((ext_vector_type(4)));
typedef float   f32x2   __attribute__((ext_vector_type(2)));
typedef unsigned short ushortx8 __attribute__((ext_vector_type(8)));

__device__ __forceinline__ float gelu_f(float v) {
    // tanh-form gelu: |err| <~2e-3, << fp8 step.
    float u = v * fmaf(0.0713548354f, v * v, 1.5957691216f);
    float t = __expf(u);
    float r = __builtin_amdgcn_rcpf(t + 1.0f);
    return v - v * r;
}
__device__ __forceinline__ unsigned char f32_to_fp8(float v) {
    __hip_fp8_e4m3 t(v);
    return (unsigned char)t.__x;
}
__device__ __forceinline__ float fp8_to_f32(unsigned char u) {
    __hip_fp8_e4m3 t;
    t.__x = (__hip_fp8_storage_t)u;
    return (float)t;
}

#if __has_builtin(__builtin_amdgcn_cvt_pk_f32_fp8) && __has_builtin(__builtin_amdgcn_cvt_pk_fp8_f32)
#define HW_FP8 1
#endif
template<bool HI>
__device__ __forceinline__ f32x2 fp8x2_f32(unsigned int u) {
#ifdef HW_FP8
    return __builtin_amdgcn_cvt_pk_f32_fp8((int)u, HI);
#else
    f32x2 r;
    const int s = HI ? 16 : 0;
    r.x = fp8_to_f32((unsigned char)(u >> s));
    r.y = fp8_to_f32((unsigned char)(u >> (s + 8)));
    return r;
#endif
}
template<bool HI>
__device__ __forceinline__ unsigned int f32x2_fp8(float a, float b, unsigned int old) {
#ifdef HW_FP8
    return (unsigned int)__builtin_amdgcn_cvt_pk_fp8_f32(a, b, (int)old, HI);
#else
    unsigned int v = (unsigned int)f32_to_fp8(a) | ((unsigned int)f32_to_fp8(b) << 8);
    return HI ? ((old & 0x0000ffffu) | (v << 16)) : ((old & 0xffff0000u) | v);
#endif
}

__device__ __forceinline__ unsigned short f2bf(float f) {   // RNE, matches HW
    unsigned int u = __builtin_bit_cast(unsigned int, f);
    u += 0x7fffu + ((u >> 16) & 1u);
    return (unsigned short)(u >> 16);
}
__device__ __forceinline__ float bf2f(unsigned short u) {
    return __builtin_bit_cast(float, ((unsigned int)u) << 16);
}
// packed f32x2 -> 2x bf16 in one dword (lo = a, hi = b); RNE, matches f2bf.
__device__ __forceinline__ unsigned int cvt_pk_bf16(float a, float b) {
#if defined(__gfx950__)
    unsigned int r;
    asm("v_cvt_pk_bf16_f32 %0, %1, %2" : "=v"(r) : "v"(a), "v"(b));
    return r;
#else
    return (unsigned int)f2bf(a) | ((unsigned int)f2bf(b) << 16);
#endif
}

// ---------------------------------------------------------------------------
// Kernel 0: one-time weight conversion to bf16.
// ---------------------------------------------------------------------------
__global__ __launch_bounds__(256) void k_prep(
        const float* __restrict__ qkvw, const float* __restrict__ projw,
        const float* __restrict__ rpb,  const float* __restrict__ fc1w,
        unsigned short* __restrict__ qkvw_bf, unsigned short* __restrict__ projw_bf,
        unsigned short* __restrict__ rpb_bf,  unsigned short* __restrict__ fc1w_bf) {
    const int i = blockIdx.x * 256 + threadIdx.x;   // grid 64*256 = 16384
    if (i < 12288) qkvw_bf[i] = f2bf(qkvw[i]);
    if (i < 4096)  projw_bf[i] = f2bf(projw[i]);
    if (i < 900)   rpb_bf[i]   = f2bf(rpb[i]);
    if (i < 16384) fc1w_bf[i]  = f2bf(fc1w[i]);
}

__global__ __launch_bounds__(256) void k_cvt(const float* __restrict__ src,
        unsigned short* __restrict__ dst, int n) {
    const int i = blockIdx.x * 256 + threadIdx.x;
    if (i < n) dst[i] = f2bf(src[i]);
}

// ---------------------------------------------------------------------------
// Kernel 2: fused LN1 + windowed attention, MFMA bf16.
// R9: XCD-aware swizzle (widx = (bid&7)*512 + bid>>3) so windows that share
// x cache lines land on the same XCD's L2; qkvw prefetched to registers at
// kernel start (latency hidden under LN phase).
// ---------------------------------------------------------------------------
__global__ __launch_bounds__(256) void k_attn(
        const float* __restrict__ x,
        const float* __restrict__ n1w, const float* __restrict__ n1b,
        const unsigned short* __restrict__ qkvw_bf,
        const unsigned short* __restrict__ projw_bf,
        const unsigned short* __restrict__ rpb_bf,
        const float* __restrict__ qkvb,
        const float* __restrict__ projb,
        unsigned short* __restrict__ Cb) {
    __shared__ __align__(16) unsigned short Xs[4608];    // [64][72]; LN: red0/red1
    __shared__ __align__(16) unsigned short Ws[13824];   // rawT f32 -> W -> QKV/P/projw
    __shared__ __align__(8)  unsigned short rpbl[900];
    __shared__ float qkvbl[192];                         // LN: lnw/lnb/rs -> qkv bias
    __shared__ float projbl[64];                         // LN: mu -> proj bias

    const int tid = threadIdx.x;
    const int lane = tid & 63, wv = tid >> 6;
    const int l15 = lane & 15, quad = lane >> 4;
    const int bid = blockIdx.x;
    const int widx = ((bid & 7) << 9) + (bid >> 3);      // XCD swizzle (bijective)
    const int wib = widx & 1023;
    const int wy = wib >> 5, wx = wib & 31, bimg = widx >> 10;
    const bool edge = (wy == 31) | (wx == 31);

    const f32x4 zz = {0.f, 0.f, 0.f, 0.f};
    const ushortx8 zu = {0, 0, 0, 0, 0, 0, 0, 0};
    const bf16x8 z8 = __builtin_bit_cast(bf16x8, zu);
    const ushortx8 ou = {0x3F80, 0x3F80, 0x3F80, 0x3F80, 0x3F80, 0x3F80, 0x3F80, 0x3F80};
    const bf16x8 ones8 = __builtin_bit_cast(bf16x8, ou);

    float* rawT = (float*)Ws;                 // [64 ch][68] f32 (17408B <= 27648B)
    float* red0 = (float*)Xs;                 // [256]
    float* red1 = red0 + 256;                 // [256]
    float* lnw  = qkvbl;                      // [64]
    float* lnb  = qkvbl + 64;                 // [64]
    float* rsv  = qkvbl + 128;                // [64]
    float* muv  = projbl;                     // [64]

    // register-held biases (LDS slots busy during LN phase)
    float qb = 0.f, pb = 0.f;
    if (tid < 192) qb = qkvb[tid];
    if (tid < 64)  pb = projb[tid];
    if (tid < 64)  { lnw[tid] = n1w[tid]; lnb[tid] = n1b[tid]; }

    // prefetch qkvw (6 granules/thread, written to Ws after B_c) and projw
    ushortx8 qw[6];
    #pragma unroll
    for (int it = 0; it < 6; ++it)
        qw[it] = *(const ushortx8*)(qkvw_bf + (it * 256 + tid) * 8);
    const ushortx8 pw0 = *(const ushortx8*)(projw_bf + tid * 8);
    const ushortx8 pw1 = *(const ushortx8*)(projw_bf + (256 + tid) * 8);

    if (tid < 225) *(uint2*)&rpbl[tid * 4] = *(const uint2*)(rpb_bf + tid * 4);

    // stage x: 1024 units = 64ch x 8py x 2half; float4 each; wrap via &255
    {
        const float* xb = x + (((size_t)bimg * 64) << 16);
        #pragma unroll
        for (int it = 0; it < 4; ++it) {
            const int u = it * 256 + tid;
            const int ch = u >> 4, py = (u >> 1) & 7, half = u & 1;
            const int iy = (wy * 8 + py + 4) & 255;
            const int col0 = (wx * 8 + 4 + half * 4) & 255;
            const float4 v = *(const float4*)(xb + ((size_t)ch << 16) + iy * 256 + col0);
            f32x4 w4 = {v.x, v.y, v.z, v.w};
            *(f32x4*)&rawT[ch * 68 + py * 8 + half * 4] = w4;
        }
    }
    __syncthreads();                                // B_a (rawT visible)

    // LN stats: tokens are columns of rawT
    {
        const int tk = tid & 63, cl = tid >> 6;
        float s = 0.f, s2 = 0.f;
        #pragma unroll
        for (int k = 0; k < 16; ++k) {
            float v = rawT[(cl * 16 + k) * 68 + tk];
            s += v; s2 += v * v;
        }
        red0[cl * 64 + tk] = s; red1[cl * 64 + tk] = s2;
    }
    __syncthreads();                                // B_b
    if (tid < 64) {
        float s  = red0[tid] + red0[64 + tid] + red0[128 + tid] + red0[192 + tid];
        float s2 = red1[tid] + red1[64 + tid] + red1[128 + tid] + red1[192 + tid];
        float mu = s * (1.f / 64.f);
        float var = s2 * (1.f / 64.f) - mu * mu;
        muv[tid] = mu; rsv[tid] = rsqrtf(var + 1e-5f);
    }
    __syncthreads();                                // B_b2

    // normalize -> Xs (paired channels, cvt_pk); extract residual to regs
    {
        const int cp = tid & 31, ch0 = cp * 2, tl = tid >> 5;
        const float lw0 = lnw[ch0], lw1 = lnw[ch0 + 1];
        const float lb0 = lnb[ch0], lb1 = lnb[ch0 + 1];
        #pragma unroll
        for (int it = 0; it < 8; ++it) {
            const int t = tl + 8 * it;
            const float v0 = rawT[ch0 * 68 + t];
            const float v1 = rawT[(ch0 + 1) * 68 + t];
            const float mu = muv[t], rs = rsv[t];
            const float vn0 = (v0 - mu) * rs * lw0 + lb0;
            const float vn1 = (v1 - mu) * rs * lw1 + lb1;
            *(unsigned int*)&Xs[t * 72 + ch0] = cvt_pk_bf16(vn0, vn1);
        }
    }
    float residf[16];
    #pragma unroll
    for (int r = 0; r < 4; ++r) {
        const int tok = 16 * wv + quad * 4 + r;
        #pragma unroll
        for (int nt = 0; nt < 4; ++nt)
            residf[r * 4 + nt] = rawT[(nt * 16 + l15) * 68 + tok];
    }
    __syncthreads();                                // B_c (rawT/mu/rs dead)

    // restore bias tables; write prefetched qkvw into Ws
    if (tid < 192) qkvbl[tid] = qb;
    if (tid < 64)  projbl[tid] = pb;
    #pragma unroll
    for (int it = 0; it < 6; ++it) {
        int g = it * 256 + tid;
        int row = g >> 3, c8 = g & 7;
        *(ushortx8*)&Ws[row * 72 + c8 * 8] = qw[it];
    }
    __syncthreads();                                // B1

    // QKV: 24 MFMA/thread
    f32x4 qacc[12];
    #pragma unroll
    for (int i = 0; i < 12; ++i) qacc[i] = zz;
    {
        const bf16x8 av0 = *(const bf16x8*)&Xs[(16 * wv + l15) * 72 + quad * 8];
        const bf16x8 av1 = *(const bf16x8*)&Xs[(16 * wv + l15) * 72 + 32 + quad * 8];
        #pragma unroll
        for (int gl = 0; gl < 12; ++gl) {
            bf16x8 bv0 = *(const bf16x8*)&Ws[(gl * 16 + l15) * 72 + quad * 8];
            qacc[gl] = __builtin_amdgcn_mfma_f32_16x16x32_bf16(av0, bv0, qacc[gl], 0, 0, 0);
            bf16x8 bv1 = *(const bf16x8*)&Ws[(gl * 16 + l15) * 72 + 32 + quad * 8];
            qacc[gl] = __builtin_amdgcn_mfma_f32_16x16x32_bf16(av1, bv1, qacc[gl], 0, 0, 0);
        }
    }
    __syncthreads();                                // B2 (all W reads done)

    // write Q (scaled) / K / V into Ws
    #pragma unroll
    for (int g = 0; g < 12; ++g) {
        #pragma unroll
        for (int r = 0; r < 4; ++r) {
            int tok = 16 * wv + quad * 4 + r;
            int oc  = g * 16 + l15;
            float v = qacc[g][r] + qkvbl[oc];
            if (g < 4)       Ws[g * 1024 + tok * 16 + l15] = f2bf(v * 0.25f);
            else if (g < 8)  Ws[4096 + (g - 4) * 1024 + tok * 16 + l15] = f2bf(v);
            else             Ws[8192 + ((g - 8) * 16 + l15) * 72 + tok] = f2bf(v);
        }
    }
    __syncthreads();                                // B3

    // S = Q K^T
    f32x4 sacc[4][4];
    #pragma unroll
    for (int h = 0; h < 4; ++h) {
        bf16x8 qa = z8;
        if (quad < 2) qa = *(const bf16x8*)&Ws[h * 1024 + (16 * wv + l15) * 16 + quad * 8];
        #pragma unroll
        for (int nt = 0; nt < 4; ++nt) {
            bf16x8 kf = z8;
            if (quad < 2) kf = *(const bf16x8*)&Ws[4096 + h * 1024 + (nt * 16 + l15) * 16 + quad * 8];
            sacc[h][nt] = __builtin_amdgcn_mfma_f32_16x16x32_bf16(qa, kf, zz, 0, 0, 0);
        }
    }
    __syncthreads();                                // B4

    // stage projw into the dead K region, XOR-swizzled [oc][64]
    {
        const int r0 = tid >> 3;
        *(ushortx8*)&Ws[4096 + r0 * 64 + (((tid & 7) ^ (r0 & 7)) << 3)] = pw0;
        const int g1 = 256 + tid, r1 = g1 >> 3;
        *(ushortx8*)&Ws[4096 + r1 * 64 + (((g1 & 7) ^ (r1 & 7)) << 3)] = pw1;
    }

    const int jhi = l15 >> 3, jlo = l15 & 7;
    int offj4[4], regj[4];
    #pragma unroll
    for (int nt = 0; nt < 4; ++nt) {
        int j = nt * 16 + l15;
        int jy = j >> 3, jx = j & 7;
        offj4[nt] = (jy * 15 + jx) * 4;
        regj[nt] = 0;
        if (edge) {
            int ysj = wy * 8 + jy, xsj = wx * 8 + jx;
            regj[nt] = (ysj >= 252 ? 2 : (ysj >= 248 ? 1 : 0)) * 3
                     + (xsj >= 252 ? 2 : (xsj >= 248 ? 1 : 0));
        }
    }
    int rbA[4], regiA[4], pbaseA[4], i7A[4];
    #pragma unroll
    for (int r = 0; r < 4; ++r) {
        const int i = 16 * wv + quad * 4 + r;
        const int iy = i >> 3, ix = i & 7;
        rbA[r] = ((iy + 7) * 15 + (ix + 7)) * 4;
        i7A[r] = i & 7;
        pbaseA[r] = i * 64 + jlo;
        regiA[r] = 0;
        if (edge) {
            const int ysi = wy * 8 + iy, xsi = wx * 8 + ix;
            regiA[r] = (ysi >= 252 ? 2 : (ysi >= 248 ? 1 : 0)) * 3
                     + (xsi >= 252 ? 2 : (xsi >= 248 ? 1 : 0));
        }
    }

    #pragma unroll
    for (int r = 0; r < 4; ++r) {
        #pragma unroll
        for (int nt = 0; nt < 4; ++nt) {
            const uint2 bw = *(const uint2*)&rpbl[rbA[r] - offj4[nt]];
            float mk = 0.f;
            if (edge) mk = (regj[nt] == regiA[r]) ? 0.f : -100.f;
            sacc[0][nt][r] += __builtin_bit_cast(float, bw.x << 16) + mk;
            sacc[1][nt][r] += __builtin_bit_cast(float, bw.x & 0xffff0000u) + mk;
            sacc[2][nt][r] += __builtin_bit_cast(float, bw.y << 16) + mk;
            sacc[3][nt][r] += __builtin_bit_cast(float, bw.y & 0xffff0000u) + mk;
        }
    }
    int pA_[4][4];
    #pragma unroll
    for (int r = 0; r < 4; ++r)
        #pragma unroll
        for (int nt = 0; nt < 4; ++nt)
            pA_[r][nt] = pbaseA[r] + ((((nt << 1) | jhi) ^ i7A[r]) << 3);

    // per-head: exp (no reductions) -> P bf16 (unnormalized) -> PV + ones-MFMA
    f32x4 o[4];
    #pragma unroll
    for (int h = 0; h < 4; ++h) {
        #pragma unroll
        for (int r = 0; r < 4; ++r) {
            const unsigned int pk01 = cvt_pk_bf16(__expf(sacc[h][0][r]),
                                                  __expf(sacc[h][1][r]));
            const unsigned int pk23 = cvt_pk_bf16(__expf(sacc[h][2][r]),
                                                  __expf(sacc[h][3][r]));
            Ws[pA_[r][0]] = (unsigned short)pk01;
            Ws[pA_[r][1]] = (unsigned short)(pk01 >> 16);
            Ws[pA_[r][2]] = (unsigned short)pk23;
            Ws[pA_[r][3]] = (unsigned short)(pk23 >> 16);
        }
        o[h] = zz;
        f32x4 os = zz;
        #pragma unroll
        for (int s = 0; s < 2; ++s) {
            bf16x8 pa = *(const bf16x8*)&Ws[(16 * wv + l15) * 64
                                            + (((s * 4 + quad) ^ (l15 & 7)) << 3)];
            bf16x8 vb = *(const bf16x8*)&Ws[8192 + (h * 16 + l15) * 72 + s * 32 + quad * 8];
            o[h] = __builtin_amdgcn_mfma_f32_16x16x32_bf16(pa, vb, o[h], 0, 0, 0);
            os   = __builtin_amdgcn_mfma_f32_16x16x32_bf16(pa, ones8, os, 0, 0, 0);
        }
        #pragma unroll
        for (int r = 0; r < 4; ++r) o[h][r] *= __builtin_amdgcn_rcpf(os[r]);
    }

    // o -> Xs (own rows only)
    #pragma unroll
    for (int h = 0; h < 4; ++h)
        #pragma unroll
        for (int r = 0; r < 4; ++r)
            Xs[(16 * wv + quad * 4 + r) * 72 + h * 16 + l15] = f2bf(o[h][r]);
    __syncthreads();                                // B5

    // proj: 8 MFMA/thread
    f32x4 pacc[4];
    #pragma unroll
    for (int nt = 0; nt < 4; ++nt) {
        pacc[nt] = zz;
        #pragma unroll
        for (int s = 0; s < 2; ++s) {
            bf16x8 oa = *(const bf16x8*)&Xs[(16 * wv + l15) * 72 + s * 32 + quad * 8];
            bf16x8 wb = *(const bf16x8*)&Ws[4096 + (nt * 16 + l15) * 64
                                            + (((s * 4 + quad) ^ (l15 & 7)) << 3)];
            pacc[nt] = __builtin_amdgcn_mfma_f32_16x16x32_bf16(oa, wb, pacc[nt], 0, 0, 0);
        }
    }

    // epilogue: bias + residual (f32, from registers), un-shift, store Cb
    #pragma unroll
    for (int r = 0; r < 4; ++r) {
        int tok = 16 * wv + quad * 4 + r;
        int py = tok >> 3, px = tok & 7;
        int yo = (wy * 8 + py + 4) & 255, xo = (wx * 8 + px + 4) & 255;
        size_t gt = ((size_t)bimg << 16) + yo * 256 + xo;
        #pragma unroll
        for (int nt = 0; nt < 4; ++nt) {
            int oc = nt * 16 + l15;
            float v = pacc[nt][r] + projbl[oc] + residf[r * 4 + nt];
            Cb[gt * 64 + oc] = f2bf(v);
        }
    }
}

// ---------------------------------------------------------------------------
// Kernel 3: LN2 + fc1 + GELU -> D (image layout fp8), MFMA bf16 (R7).
// ---------------------------------------------------------------------------
__global__ __launch_bounds__(256) void k_ln2fc1(const unsigned short* __restrict__ Cb,
        const float* __restrict__ w2, const float* __restrict__ b2,
        const unsigned short* __restrict__ fc1w_bf, const float* __restrict__ fc1b,
        unsigned char* __restrict__ D) {
    __shared__ __align__(16) unsigned short Xb[64 * 72];    // raw->normalized bf16
    __shared__ __align__(16) unsigned short Wb[256 * 72];   // fc1w bf16; tail reuse: stT
    __shared__ float red0[256], red1[256];
    __shared__ float muv[64], rsv[64], lwv[64], lbv[64], fb[256];
    const int tid = threadIdx.x, gid = blockIdx.x;
    const int xc = gid & 3, y = (gid >> 2) & 255, b = gid >> 10;
    const int x0 = xc * 64;
    const int lane = tid & 63, wv = tid >> 6;
    const int l15 = lane & 15, quad = lane >> 4;
    const f32x4 zz = {0.f, 0.f, 0.f, 0.f};

    if (tid < 64) { lwv[tid] = w2[tid]; lbv[tid] = b2[tid]; }
    fb[tid] = fc1b[tid];

    // stage Cb -> Xb (b128, 2 passes)
    const unsigned short* Cp = Cb + ((size_t)(b << 16) + y * 256 + x0) * 64;
    #pragma unroll
    for (int it = 0; it < 2; ++it) {
        const int g = it * 256 + tid;               // granule 0..511
        const int row = g >> 3, c8 = g & 7;
        *(ushortx8*)&Xb[row * 72 + c8 * 8] = *(const ushortx8*)(Cp + g * 8);
    }
    // stage fc1w_bf -> Wb (b128)
    {
        const ushortx8* w8 = (const ushortx8*)fc1w_bf;
        #pragma unroll
        for (int it = 0; it < 8; ++it) {
            int idx = it * 256 + tid;
            int row = idx >> 3, c8 = idx & 7;
            *(ushortx8*)&Wb[row * 72 + c8 * 8] = w8[idx];
        }
    }
    __syncthreads();
    // LN stats from bf16 tile
    {
        const int tok = tid & 63, cl = tid >> 6;
        float s = 0.f, s2 = 0.f;
        #pragma unroll
        for (int g = 0; g < 2; ++g) {
            const ushortx8 u = *(const ushortx8*)&Xb[tok * 72 + cl * 16 + g * 8];
            #pragma unroll
            for (int k = 0; k < 8; ++k) { float v = bf2f(u[k]); s += v; s2 += v * v; }
        }
        red0[cl * 64 + tok] = s; red1[cl * 64 + tok] = s2;
    }
    __syncthreads();
    if (tid < 64) {
        float s  = red0[tid] + red0[64 + tid] + red0[128 + tid] + red0[192 + tid];
        float s2 = red1[tid] + red1[64 + tid] + red1[128 + tid] + red1[192 + tid];
        float mu = s * (1.f / 64.f);
        float var = s2 * (1.f / 64.f) - mu * mu;
        muv[tid] = mu; rsv[tid] = rsqrtf(var + 1e-5f);
    }
    __syncthreads();
    // normalize in place (vectorized: b128 read/write, cvt_pk pack)
    {
        const int c8n = tid & 7;
        const float4 lwa = *(const float4*)&lwv[c8n * 8];
        const float4 lwb2 = *(const float4*)&lwv[c8n * 8 + 4];
        const float4 lba = *(const float4*)&lbv[c8n * 8];
        const float4 lbb2 = *(const float4*)&lbv[c8n * 8 + 4];
        const float lw8[8] = {lwa.x, lwa.y, lwa.z, lwa.w, lwb2.x, lwb2.y, lwb2.z, lwb2.w};
        const float lb8[8] = {lba.x, lba.y, lba.z, lba.w, lbb2.x, lbb2.y, lbb2.z, lbb2.w};
        #pragma unroll
        for (int it = 0; it < 2; ++it) {
            const int row = it * 32 + (tid >> 3);
            const ushortx8 u = *(const ushortx8*)&Xb[row * 72 + c8n * 8];
            const float mu = muv[row], rs = rsv[row];
            float v[8];
            #pragma unroll
            for (int k = 0; k < 8; ++k) v[k] = (bf2f(u[k]) - mu) * rs * lw8[k] + lb8[k];
            uint4 pk;
            pk.x = cvt_pk_bf16(v[0], v[1]); pk.y = cvt_pk_bf16(v[2], v[3]);
            pk.z = cvt_pk_bf16(v[4], v[5]); pk.w = cvt_pk_bf16(v[6], v[7]);
            *(uint4*)&Xb[row * 72 + c8n * 8] = pk;
        }
    }
    __syncthreads();

    // MFMA: acc[mt][nt], m = 64wv+16mt (hidden ch), n = 16nt (token), K=64
    f32x4 acc[4][4];
    #pragma unroll
    for (int mt = 0; mt < 4; ++mt)
        #pragma unroll
        for (int nt = 0; nt < 4; ++nt) acc[mt][nt] = zz;
    #pragma unroll
    for (int s = 0; s < 2; ++s) {
        bf16x8 Bf[4];
        #pragma unroll
        for (int nt = 0; nt < 4; ++nt)
            Bf[nt] = *(const bf16x8*)&Xb[(nt * 16 + l15) * 72 + s * 32 + quad * 8];
        #pragma unroll
        for (int mt = 0; mt < 4; ++mt) {
            bf16x8 Af = *(const bf16x8*)&Wb[(64 * wv + 16 * mt + l15) * 72 + s * 32 + quad * 8];
            #pragma unroll
            for (int nt = 0; nt < 4; ++nt)
                acc[mt][nt] = __builtin_amdgcn_mfma_f32_16x16x32_bf16(Af, Bf[nt], acc[mt][nt], 0, 0, 0);
        }
    }

    // epilogue: bias + gelu + fp8 pack -> wave-private LDS transpose ->
    // coalesced u32 stores.
    unsigned int* stT = (unsigned int*)&Wb[(size_t)(64 * wv) * 72]; // [16][20] u32
    const int s4 = lane >> 4;
    #pragma unroll
    for (int mt = 0; mt < 4; ++mt) {
        #pragma unroll
        for (int r = 0; r < 4; ++r) {
            const int mch = 64 * wv + 16 * mt + quad * 4 + r;
            const float bias = fb[mch];
            float g0 = gelu_f(acc[mt][0][r] + bias);
            float g1 = gelu_f(acc[mt][1][r] + bias);
            float g2 = gelu_f(acc[mt][2][r] + bias);
            float g3 = gelu_f(acc[mt][3][r] + bias);
            unsigned int pk = f32x2_fp8<false>(g0, g1, 0u);
            pk = f32x2_fp8<true>(g2, g3, pk);
            stT[(quad * 4 + r) * 20 + l15] = pk;
        }
        const int orow = l15;
        const uint4 w = *(const uint4*)&stT[orow * 20 + 4 * s4];
        const int mch2 = 64 * wv + 16 * mt + orow;
        unsigned char* Dp2 = D + (((size_t)(b * 256 + mch2)) << 16) + y * 256 + x0;
        #pragma unroll
        for (int p = 0; p < 4; ++p) {
            unsigned int o = ((w.x >> (8 * p)) & 0xffu)
                           | (((w.y >> (8 * p)) & 0xffu) << 8)
                           | (((w.z >> (8 * p)) & 0xffu) << 16)
                           | (((w.w >> (8 * p)) & 0xffu) << 24);
            *(unsigned int*)&Dp2[16 * p + 4 * s4] = o;
        }
    }
}

// ---------------------------------------------------------------------------
// Kernel 4: depthwise 5x5 conv + GELU + residual via MFMA (banded matmul, R7).
// ---------------------------------------------------------------------------
__global__ __launch_bounds__(256) void k_dwconv(const unsigned char* __restrict__ D,
        const float* __restrict__ dww, const float* __restrict__ dwb,
        unsigned char* __restrict__ E) {
    __shared__ __align__(16) unsigned short inT[36 * 280 + 16]; // [t][2+x]
    __shared__ __align__(16) unsigned short Atab[5 * 64 * 8];   // A frags per ky
    __shared__ __align__(16) unsigned char outT[4][16 * 144];   // per-wave staging
    const int tid = threadIdx.x, gid = blockIdx.x;
    const int yt = gid & 7, pc = gid >> 3;        // grid 8192
    const int ch = pc & 255;
    const int y0 = yt * 32;
    const unsigned char* Dp = D + ((size_t)pc << 16);
    const f32x4 zz = {0.f, 0.f, 0.f, 0.f};

    // pad columns: dword 0 + dwords 129..139
    for (int idx = tid; idx < 432; idx += 256) {
        const int r = idx / 12, c = idx - r * 12;
        const int dw = (c == 0) ? 0 : (128 + c);
        ((unsigned int*)&inT[r * 280])[dw] = 0u;
    }
    // stage D (fp8) -> inT (bf16); OOB rows write zeros
    #pragma unroll
    for (int it = 0; it < 9; ++it) {
        const int u = it * 256 + tid;
        const int t = u >> 6, c = u & 63;
        const int gy = y0 - 2 + t;
        unsigned int v = 0u;
        if ((unsigned)gy < 256u) v = *(const unsigned int*)(Dp + gy * 256 + 4 * c);
        const f32x2 lo = fp8x2_f32<false>(v);
        const f32x2 hi = fp8x2_f32<true>(v);
        unsigned int* base = (unsigned int*)&inT[t * 280 + 2 + 4 * c];
        base[0] = cvt_pk_bf16(lo.x, lo.y);
        base[1] = cvt_pk_bf16(hi.x, hi.y);
    }
    // A-fragment table
    #pragma unroll
    for (int q = 0; q < 10; ++q) {
        const int e = tid * 10 + q;               // 0..2559
        const int ky = e >> 9, r = e & 511;
        const int l = r >> 3, j = r & 7;
        const int m = l & 15, k = ((l >> 4) << 3) + j;
        const int d = k - m;
        float wv = 0.f;
        if (d >= 0 && d < 5) wv = dww[ch * 25 + ky * 5 + d];
        Atab[e] = f2bf(wv);
    }
    const float bb = dwb[ch];
    __syncthreads();

    const int wv_ = tid >> 6, lane = tid & 63;
    const int l15 = lane & 15, quad = lane >> 4;
    const int g = wv_ >> 1, xh = wv_ & 1;
    bf16x8 Af[5];
    #pragma unroll
    for (int ky = 0; ky < 5; ++ky)
        Af[ky] = *(const bf16x8*)&Atab[(ky * 64 + lane) * 8];
    const int tbase = g * 16 + l15;

    #pragma unroll
    for (int xp = 0; xp < 8; ++xp) {
        const int xs = xh * 128 + xp * 16;
        f32x4 acc = zz;
        #pragma unroll
        for (int ky = 0; ky < 5; ++ky) {
            bf16x8 Bf = *(const bf16x8*)&inT[(tbase + ky) * 280 + xs + quad * 8];
            acc = __builtin_amdgcn_mfma_f32_16x16x32_bf16(Af[ky], Bf, acc, 0, 0, 0);
        }
        const unsigned int* cp32 = (const unsigned int*)&inT[(tbase + 2) * 280 + 2 + xs + quad * 4];
        const unsigned int c01 = cp32[0], c23 = cp32[1];
        const float c0 = bf2f((unsigned short)c01), c1 = bf2f((unsigned short)(c01 >> 16));
        const float c2 = bf2f((unsigned short)c23), c3 = bf2f((unsigned short)(c23 >> 16));
        unsigned int pk = f32x2_fp8<false>(c0 + gelu_f(acc[0] + bb), c1 + gelu_f(acc[1] + bb), 0u);
        pk = f32x2_fp8<true>(c2 + gelu_f(acc[2] + bb), c3 + gelu_f(acc[3] + bb), pk);
        *(unsigned int*)&outT[wv_][l15 * 144 + xp * 16 + quad * 4] = pk;
    }

    {
        const int row = lane >> 2, sg = lane & 3;
        unsigned char* Ep = E + ((size_t)pc << 16) + (y0 + g * 16 + row) * 256 + xh * 128 + sg * 32;
        *(uint4*)Ep        = *(const uint4*)&outT[wv_][row * 144 + sg * 32];
        *(uint4*)(Ep + 16) = *(const uint4*)&outT[wv_][row * 144 + sg * 32 + 16];
    }
}

// ---------------------------------------------------------------------------
// Kernel 5: fc2 + bias + residual + transpose -> out (b,c,h,w) fp32, MFMA (R7).
// ---------------------------------------------------------------------------
__global__ __launch_bounds__(256) void k_fc2(const unsigned char* __restrict__ E,
        const unsigned short* __restrict__ Cb, const unsigned short* __restrict__ fc2w_bf,
        const float* __restrict__ fc2b, float* __restrict__ out) {
    __shared__ __align__(16) unsigned short Hb[64 * 136];   // [tok][k128 swz]
    __shared__ __align__(16) unsigned short Wb2[64 * 264];  // [oc][k256]
    __shared__ __align__(16) unsigned short Cl[64 * 72];    // residual raw bf16
    __shared__ float fbl[64];
    const int tid = threadIdx.x, gid = blockIdx.x;
    const int xc = gid & 3, y = (gid >> 2) & 255, b = gid >> 10;
    const int x0 = xc * 64;
    const int lane = tid & 63, wv = tid >> 6;
    const int l15 = lane & 15, quad = lane >> 4;
    const f32x4 zz = {0.f, 0.f, 0.f, 0.f};

    if (tid < 64) fbl[tid] = fc2b[tid];
    {
        const unsigned short* Cp = Cb + ((size_t)(b << 16) + y * 256 + x0) * 64;
        #pragma unroll
        for (int it = 0; it < 2; ++it) {
            const int g = it * 256 + tid;
            const int row = g >> 3, c8 = g & 7;
            *(ushortx8*)&Cl[row * 72 + c8 * 8] = *(const ushortx8*)(Cp + g * 8);
        }
    }
    {
        const ushortx8* w8 = (const ushortx8*)fc2w_bf;
        #pragma unroll
        for (int it = 0; it < 8; ++it) {
            int idx = it * 256 + tid;
            int row = idx >> 5, c8 = idx & 31;
            *(ushortx8*)&Wb2[row * 264 + c8 * 8] = w8[idx];
        }
    }

    f32x4 acc[4];
    #pragma unroll
    for (int nt = 0; nt < 4; ++nt) acc[nt] = zz;

    const int ldc = tid >> 4;
    const int tq  = tid & 15;
    unsigned int u0[8];
    #pragma unroll
    for (int it = 0; it < 8; ++it) {
        int chl = ldc + 16 * it;
        u0[it] = *(const unsigned int*)&E[(((size_t)(b * 256 + chl)) << 16) + y * 256 + x0 + 4 * tq];
    }
    __syncthreads();

    for (int kc = 0; kc < 2; ++kc) {
        #pragma unroll
        for (int it = 0; it < 8; ++it) {
            int chl = ldc + 16 * it;
            f32x2 lo = fp8x2_f32<false>(u0[it]);
            f32x2 hi = fp8x2_f32<true>(u0[it]);
            const unsigned int p01 = cvt_pk_bf16(lo.x, lo.y);
            const unsigned int p23 = cvt_pk_bf16(hi.x, hi.y);
            unsigned short hs[4] = {(unsigned short)p01, (unsigned short)(p01 >> 16),
                                    (unsigned short)p23, (unsigned short)(p23 >> 16)};
            #pragma unroll
            for (int j = 0; j < 4; ++j) {
                int tok = 4 * tq + j;
                int p = (((chl >> 3) ^ (tok >> 2)) << 3) + (chl & 7);
                Hb[tok * 136 + p] = hs[j];
            }
        }
        if (kc == 0) {
            #pragma unroll
            for (int it = 0; it < 8; ++it) {
                int chl = ldc + 16 * it + 128;
                u0[it] = *(const unsigned int*)&E[(((size_t)(b * 256 + chl)) << 16) + y * 256 + x0 + 4 * tq];
            }
        }
        __syncthreads();
        #pragma unroll
        for (int k32 = 0; k32 < 4; ++k32) {
            bf16x8 Af = *(const bf16x8*)&Wb2[(16 * wv + l15) * 264 + kc * 128 + k32 * 32 + quad * 8];
            const int g = k32 * 4 + quad;
            #pragma unroll
            for (int nt = 0; nt < 4; ++nt) {
                const int tok = nt * 16 + l15;
                bf16x8 Bf = *(const bf16x8*)&Hb[tok * 136 + ((g ^ (tok >> 2)) << 3)];
                acc[nt] = __builtin_amdgcn_mfma_f32_16x16x32_bf16(Af, Bf, acc[nt], 0, 0, 0);
            }
        }
        if (kc == 0) __syncthreads();
    }

    #pragma unroll
    for (int r = 0; r < 4; ++r) {
        const int oc = 16 * wv + quad * 4 + r;
        const float bias = fbl[oc];
        float* op = out + (((size_t)(b * 64 + oc)) << 16) + y * 256 + x0;
        #pragma unroll
        for (int nt = 0; nt < 4; ++nt) {
            const int tok = nt * 16 + l15;
            op[tok] = acc[nt][r] + bias + bf2f(Cl[tok * 72 + oc]);
        }
    }
}

// ---------------------------------------------------------------------------
extern "C" void kernel_launch(void* const* d_in, const int* in_sizes, int n_in,
                              void* d_out, int out_size, void* d_ws, size_t ws_size,
                              hipStream_t stream) {
    const float* x     = (const float*)d_in[0];
    const float* n1w   = (const float*)d_in[1];
    const float* n1b   = (const float*)d_in[2];
    const float* qkvw  = (const float*)d_in[3];
    const float* qkvb  = (const float*)d_in[4];
    const float* rpb   = (const float*)d_in[5];
    const float* projw = (const float*)d_in[6];
    const float* projb = (const float*)d_in[7];
    const float* n2w   = (const float*)d_in[8];
    const float* n2b   = (const float*)d_in[9];
    const float* fc1w  = (const float*)d_in[10];
    const float* fc1b  = (const float*)d_in[11];
    const float* dww   = (const float*)d_in[12];
    const float* dwb   = (const float*)d_in[13];
    const float* fc2w  = (const float*)d_in[14];
    const float* fc2b  = (const float*)d_in[15];
    float* out = (float*)d_out;

    char* ws = (char*)d_ws;
    const size_t MB = 1048576;
    unsigned short* Cbuf = (unsigned short*)ws;                  // [0,32M)
    unsigned char*  Dh   = (unsigned char*)(ws + 32 * MB);       // [32,96M)
    unsigned char*  Eh   = (unsigned char*)(ws + 96 * MB);       // [96,160M)

    unsigned short* qkvw_bf = (unsigned short*)(ws + 96 * MB);
    unsigned short* projw_bf = (unsigned short*)(ws + 96 * MB + 24576);
    unsigned short* rpb_bf   = (unsigned short*)(ws + 96 * MB + 32768);
    unsigned short* fc1w_bf  = (unsigned short*)(ws + 96 * MB + 34816);
    unsigned short* fc2w_bf  = (unsigned short*)(ws + 32 * MB);

    k_prep  <<<64,    256, 0, stream>>>(qkvw, projw, rpb, fc1w,
                                        qkvw_bf, projw_bf, rpb_bf, fc1w_bf);
    k_attn  <<<4096,  256, 0, stream>>>(x, n1w, n1b, qkvw_bf, projw_bf, rpb_bf,
                                        qkvb, projb, Cbuf);
    k_ln2fc1<<<4096,  256, 0, stream>>>(Cbuf, n2w, n2b, fc1w_bf, fc1b, Dh);
    k_dwconv<<<8192,  256, 0, stream>>>(Dh, dww, dwb, Eh);
    k_cvt   <<<64,    256, 0, stream>>>(fc2w, fc2w_bf, 16384);
    k_fc2   <<<4096,  256, 0, stream>>>(Eh, Cbuf, fc2w_bf, fc2b, out);
}